// Round 4
// baseline (320.305 us; speedup 1.0000x reference)
//
#include <hip/hip_runtime.h>
#include <cstdint>
#include <cstddef>

typedef float f32x4 __attribute__((ext_vector_type(4)));
typedef __bf16 bf16x8 __attribute__((ext_vector_type(8)));
typedef __bf16 bf16x4 __attribute__((ext_vector_type(4)));

static constexpr int BSZ = 2, SL = 2048, DM = 1024, NH = 16, HD = 64;
static constexpr int MROWS = BSZ * SL;                 // 4096
static constexpr float LOG2E = 1.4426950408889634f;
static constexpr float QSCALE = 0.03125f * LOG2E;      // D^-0.5 * log2(e)

__device__ __forceinline__ f32x4 mfma16(bf16x8 a, bf16x8 b, f32x4 c) {
    return __builtin_amdgcn_mfma_f32_16x16x32_bf16(a, b, c, 0, 0, 0);
}

// ---------- cast f32 -> bf16, vectorized x4 ----------
__global__ __launch_bounds__(256) void r4_cast(const float* __restrict__ in,
                                               __bf16* __restrict__ out, int n) {
    int i = (blockIdx.x * 256 + threadIdx.x) * 4;
    if (i >= n) return;
    float4 v = *(const float4*)&in[i];
    bf16x4 o;
    o.x = (__bf16)v.x; o.y = (__bf16)v.y; o.z = (__bf16)v.z; o.w = (__bf16)v.w;
    *(bf16x4*)&out[i] = o;
}

// ---------- transpose [R][C] f32 -> [C][R] bf16 ----------
__global__ __launch_bounds__(256) void r4_transpose_cast(const float* __restrict__ in,
                                                         __bf16* __restrict__ out,
                                                         int R, int C) {
    __shared__ float tile[32][33];
    int c0 = blockIdx.x * 32, r0 = blockIdx.y * 32;
    int tx = threadIdx.x & 31, ty = threadIdx.x >> 5;   // 256 threads: ty 0..7
#pragma unroll
    for (int i = 0; i < 32; i += 8)
        tile[ty + i][tx] = in[(size_t)(r0 + ty + i) * C + c0 + tx];
    __syncthreads();
#pragma unroll
    for (int i = 0; i < 32; i += 8)
        out[(size_t)(c0 + ty + i) * R + r0 + tx] = (__bf16)tile[tx][ty + i];
}

// ---------- GEMM: C[M,N] = A[M,K] * Bt[N,K]^T  (bf16 in, f32 acc) ----------
// EPI==1: scatter into Q (scaled), K, V^T head buffers.  EPI==0: f32 row-major out.
template <int EPI>
__global__ __launch_bounds__(256) void r4_gemm_bt(
    const __bf16* __restrict__ A, const __bf16* __restrict__ Bt,
    float* __restrict__ ob, int M, int N, int K,
    __bf16* __restrict__ qb, __bf16* __restrict__ kb, __bf16* __restrict__ vtb)
{
    constexpr int BM = 128, BN = 128, BK = 32, LDP = 40;  // pad 32->40 elems (80B rows)
    __shared__ __bf16 As[BM][LDP];
    __shared__ __bf16 Bs[BN][LDP];
    const int tid  = threadIdx.x;
    const int m0   = blockIdx.y * BM, n0 = blockIdx.x * BN;
    const int wave = tid >> 6, lane = tid & 63;
    const int lcol = lane & 15, lgrp = lane >> 4;
    const int wm   = (wave >> 1) * 64, wn = (wave & 1) * 64;

    f32x4 acc[4][4] = {};

    for (int k0 = 0; k0 < K; k0 += BK) {
#pragma unroll
        for (int i = 0; i < 2; ++i) {
            int c = tid + 256 * i;
            int row = c >> 2, off = (c & 3) * 8;
            *(int4*)&As[row][off] = *(const int4*)&A[(size_t)(m0 + row) * K + k0 + off];
            *(int4*)&Bs[row][off] = *(const int4*)&Bt[(size_t)(n0 + row) * K + k0 + off];
        }
        __syncthreads();
        bf16x8 af[4], bfr[4];
#pragma unroll
        for (int f = 0; f < 4; ++f) {
            af[f]  = *(const bf16x8*)&As[wm + f * 16 + lcol][lgrp * 8];
            bfr[f] = *(const bf16x8*)&Bs[wn + f * 16 + lcol][lgrp * 8];
        }
#pragma unroll
        for (int fm = 0; fm < 4; ++fm)
#pragma unroll
            for (int fn = 0; fn < 4; ++fn)
                acc[fm][fn] = mfma16(af[fm], bfr[fn], acc[fm][fn]);
        __syncthreads();
    }

#pragma unroll
    for (int fm = 0; fm < 4; ++fm) {
#pragma unroll
        for (int fn = 0; fn < 4; ++fn) {
            int n = n0 + wn + fn * 16 + lcol;
#pragma unroll
            for (int r = 0; r < 4; ++r) {
                int m = m0 + wm + fm * 16 + lgrp * 4 + r;
                float v = acc[fm][fn][r];
                if (EPI == 0) {
                    ob[(size_t)m * N + n] = v;               // f32 output
                } else {
                    int sec = n >> 10, nm = n & 1023;
                    int h = nm >> 6, d = nm & 63;
                    int b = m >> 11, s = m & 2047;
                    size_t bh = (size_t)(b * NH + h);
                    if (sec == 0)      qb[(bh * SL + s) * HD + d]  = (__bf16)(v * QSCALE);
                    else if (sec == 1) kb[(bh * SL + s) * HD + d]  = (__bf16)v;
                    else               vtb[(bh * HD + d) * SL + s] = (__bf16)v;
                }
            }
        }
    }
}

// ---------- flash attention: grid (qblk=32, bh=32), 4 waves x 16 q-rows ----------
__global__ __launch_bounds__(256) void r4_attn(
    const __bf16* __restrict__ qb, const __bf16* __restrict__ kb,
    const __bf16* __restrict__ vtb, __bf16* __restrict__ ctx)
{
    __shared__ __bf16 Plds[4][16][40];   // per-wave P bounce, padded rows (80B)
    const int bh   = blockIdx.y;
    const int qblk = blockIdx.x;
    const int wave = threadIdx.x >> 6, lane = threadIdx.x & 63;
    const int lcol = lane & 15, lgrp = lane >> 4;
    const int q0   = qblk * 64 + wave * 16;
    const __bf16* Q  = qb  + (size_t)bh * SL * HD;
    const __bf16* Kp = kb  + (size_t)bh * SL * HD;
    const __bf16* Vt = vtb + (size_t)bh * HD * SL;

    // Q A-frags for kd 0-31 and 32-63 (Q already scaled by D^-0.5*log2e)
    bf16x8 qa[2];
    qa[0] = *(const bf16x8*)&Q[(size_t)(q0 + lcol) * HD + lgrp * 8];
    qa[1] = *(const bf16x8*)&Q[(size_t)(q0 + lcol) * HD + 32 + lgrp * 8];

    float m_run[4], l_run[4];
    f32x4 acc[4] = {};   // acc[dg][r] : C[q=lgrp*4+r][d=dg*16+lcol]
#pragma unroll
    for (int r = 0; r < 4; ++r) { m_run[r] = -1e30f; l_run[r] = 0.f; }

    for (int kb0 = 0; kb0 < SL; kb0 += 32) {
        // S[q][kcol] (log2 domain), 2 col-groups of 16
        f32x4 s[2] = {};
#pragma unroll
        for (int cg = 0; cg < 2; ++cg) {
            bf16x8 kf0 = *(const bf16x8*)&Kp[(size_t)(kb0 + cg * 16 + lcol) * HD + lgrp * 8];
            bf16x8 kf1 = *(const bf16x8*)&Kp[(size_t)(kb0 + cg * 16 + lcol) * HD + 32 + lgrp * 8];
            s[cg] = mfma16(qa[0], kf0, s[cg]);
            s[cg] = mfma16(qa[1], kf1, s[cg]);
        }
        // online softmax: rows live across the 16 lanes of each lane-group
        float alpha[4], p[2][4];
#pragma unroll
        for (int r = 0; r < 4; ++r) {
            float mt = fmaxf(s[0][r], s[1][r]);
            mt = fmaxf(mt, __shfl_xor(mt, 1));
            mt = fmaxf(mt, __shfl_xor(mt, 2));
            mt = fmaxf(mt, __shfl_xor(mt, 4));
            mt = fmaxf(mt, __shfl_xor(mt, 8));
            float mn = fmaxf(m_run[r], mt);
            alpha[r] = exp2f(m_run[r] - mn);
            m_run[r] = mn;
            p[0][r] = exp2f(s[0][r] - mn);
            p[1][r] = exp2f(s[1][r] - mn);
            float lt = p[0][r] + p[1][r];
            lt += __shfl_xor(lt, 1);
            lt += __shfl_xor(lt, 2);
            lt += __shfl_xor(lt, 4);
            lt += __shfl_xor(lt, 8);
            l_run[r] = l_run[r] * alpha[r] + lt;
        }
#pragma unroll
        for (int dg = 0; dg < 4; ++dg)
#pragma unroll
            for (int r = 0; r < 4; ++r)
                acc[dg][r] *= alpha[r];
        // P (C-layout) -> per-wave LDS -> A-layout fragment.
#pragma unroll
        for (int cg = 0; cg < 2; ++cg)
#pragma unroll
            for (int r = 0; r < 4; ++r)
                Plds[wave][lgrp * 4 + r][cg * 16 + lcol] = (__bf16)p[cg][r];
        // Buffer is wave-private: wave-local write->read ordering is enough.
        asm volatile("s_waitcnt lgkmcnt(0)" ::: "memory");
        bf16x8 pa = *(const bf16x8*)&Plds[wave][lcol][lgrp * 8];
        // PV: ctx[q][d] += P[q][k] * V[k][d], V read from V^T (contiguous 16B)
#pragma unroll
        for (int dg = 0; dg < 4; ++dg) {
            bf16x8 vb = *(const bf16x8*)&Vt[(size_t)(dg * 16 + lcol) * SL + kb0 + lgrp * 8];
            acc[dg] = mfma16(pa, vb, acc[dg]);
        }
    }

    const int b = bh >> 4, h = bh & 15;
#pragma unroll
    for (int dg = 0; dg < 4; ++dg) {
#pragma unroll
        for (int r = 0; r < 4; ++r) {
            int q = q0 + lgrp * 4 + r;
            float o = acc[dg][r] / l_run[r];
            ctx[((size_t)b * SL + q) * DM + h * HD + dg * 16 + lcol] = (__bf16)o;
        }
    }
}

extern "C" void kernel_launch(void* const* d_in, const int* in_sizes, int n_in,
                              void* d_out, int out_size, void* d_ws, size_t ws_size,
                              hipStream_t stream) {
    const float* x    = (const float*)d_in[0];
    const float* wqkv = (const float*)d_in[1];
    const float* wout = (const float*)d_in[2];
    float* out = (float*)d_out;                          // reference returns f32

    __bf16* ws    = (__bf16*)d_ws;
    __bf16* xb    = ws;                                  // 4096*1024
    __bf16* wqkvT = xb    + (size_t)MROWS * DM;          // 3072*1024
    __bf16* woutT = wqkvT + (size_t)3 * DM * DM;         // 1024*1024
    __bf16* qbuf  = woutT + (size_t)DM * DM;             // 32*2048*64
    __bf16* kbuf  = qbuf  + (size_t)MROWS * DM;
    __bf16* vtbuf = kbuf  + (size_t)MROWS * DM;
    __bf16* ctxb  = vtbuf + (size_t)MROWS * DM;

    r4_cast<<<dim3((MROWS * DM) / 1024), dim3(256), 0, stream>>>(x, xb, MROWS * DM);
    r4_transpose_cast<<<dim3(96, 32), dim3(256), 0, stream>>>(wqkv, wqkvT, DM, 3 * DM);
    r4_transpose_cast<<<dim3(32, 32), dim3(256), 0, stream>>>(wout, woutT, DM, DM);

    r4_gemm_bt<1><<<dim3(24, 32), dim3(256), 0, stream>>>(
        xb, wqkvT, (float*)nullptr, MROWS, 3 * DM, DM, qbuf, kbuf, vtbuf);

    r4_attn<<<dim3(32, 32), dim3(256), 0, stream>>>(qbuf, kbuf, vtbuf, ctxb);

    r4_gemm_bt<0><<<dim3(8, 32), dim3(256), 0, stream>>>(
        ctxb, woutT, out, MROWS, DM, DM,
        (__bf16*)nullptr, (__bf16*)nullptr, (__bf16*)nullptr);
}

// Round 5
// 214.802 us; speedup vs baseline: 1.4912x; 1.4912x over previous
//
#include <hip/hip_runtime.h>
#include <cstdint>
#include <cstddef>

typedef float f32x4 __attribute__((ext_vector_type(4)));
typedef float f32x16 __attribute__((ext_vector_type(16)));
typedef __bf16 bf16x8 __attribute__((ext_vector_type(8)));
typedef __bf16 bf16x4 __attribute__((ext_vector_type(4)));
typedef uint32_t u32x4 __attribute__((ext_vector_type(4)));

static constexpr int BSZ = 2, SL = 2048, DM = 1024, NH = 16, HD = 64;
static constexpr int MROWS = BSZ * SL;                 // 4096
static constexpr float LOG2E = 1.4426950408889634f;
static constexpr float QSCALE = 0.03125f * LOG2E;      // D^-0.5 * log2(e)

__device__ __forceinline__ f32x4 mfma16(bf16x8 a, bf16x8 b, f32x4 c) {
    return __builtin_amdgcn_mfma_f32_16x16x32_bf16(a, b, c, 0, 0, 0);
}
__device__ __forceinline__ f32x16 mfma32(bf16x8 a, bf16x8 b, f32x16 c) {
    return __builtin_amdgcn_mfma_f32_32x32x16_bf16(a, b, c, 0, 0, 0);
}
__device__ __forceinline__ uint32_t pkbf(float lo, float hi) {
    uint16_t a = __builtin_bit_cast(uint16_t, (__bf16)lo);
    uint16_t b = __builtin_bit_cast(uint16_t, (__bf16)hi);
    return ((uint32_t)b << 16) | (uint32_t)a;
}

// ---------- cast f32 -> bf16, vectorized x4 ----------
__global__ __launch_bounds__(256) void r5_cast(const float* __restrict__ in,
                                               __bf16* __restrict__ out, int n) {
    int i = (blockIdx.x * 256 + threadIdx.x) * 4;
    if (i >= n) return;
    float4 v = *(const float4*)&in[i];
    bf16x4 o;
    o.x = (__bf16)v.x; o.y = (__bf16)v.y; o.z = (__bf16)v.z; o.w = (__bf16)v.w;
    *(bf16x4*)&out[i] = o;
}

// ---------- transpose [R][C] f32 -> [C][R] bf16 ----------
__global__ __launch_bounds__(256) void r5_transpose_cast(const float* __restrict__ in,
                                                         __bf16* __restrict__ out,
                                                         int R, int C) {
    __shared__ float tile[32][33];
    int c0 = blockIdx.x * 32, r0 = blockIdx.y * 32;
    int tx = threadIdx.x & 31, ty = threadIdx.x >> 5;   // 256 threads: ty 0..7
#pragma unroll
    for (int i = 0; i < 32; i += 8)
        tile[ty + i][tx] = in[(size_t)(r0 + ty + i) * C + c0 + tx];
    __syncthreads();
#pragma unroll
    for (int i = 0; i < 32; i += 8)
        out[(size_t)(c0 + ty + i) * R + r0 + tx] = (__bf16)tile[tx][ty + i];
}

// ---------- GEMM: C[M,N] = A[M,K] * Bt[N,K]^T  (bf16 in, f32 acc) ----------
// EPI==1: scatter into Q (scaled), K, V^T head buffers.  EPI==0: f32 row-major out.
template <int EPI>
__global__ __launch_bounds__(256) void r5_gemm_bt(
    const __bf16* __restrict__ A, const __bf16* __restrict__ Bt,
    float* __restrict__ ob, int M, int N, int K,
    __bf16* __restrict__ qb, __bf16* __restrict__ kb, __bf16* __restrict__ vtb)
{
    constexpr int BM = 128, BN = 128, BK = 32, LDP = 40;  // pad 32->40 elems (80B rows)
    __shared__ __bf16 As[BM][LDP];
    __shared__ __bf16 Bs[BN][LDP];
    const int tid  = threadIdx.x;
    const int m0   = blockIdx.y * BM, n0 = blockIdx.x * BN;
    const int wave = tid >> 6, lane = tid & 63;
    const int lcol = lane & 15, lgrp = lane >> 4;
    const int wm   = (wave >> 1) * 64, wn = (wave & 1) * 64;

    f32x4 acc[4][4] = {};

    for (int k0 = 0; k0 < K; k0 += BK) {
#pragma unroll
        for (int i = 0; i < 2; ++i) {
            int c = tid + 256 * i;
            int row = c >> 2, off = (c & 3) * 8;
            *(int4*)&As[row][off] = *(const int4*)&A[(size_t)(m0 + row) * K + k0 + off];
            *(int4*)&Bs[row][off] = *(const int4*)&Bt[(size_t)(n0 + row) * K + k0 + off];
        }
        __syncthreads();
        bf16x8 af[4], bfr[4];
#pragma unroll
        for (int f = 0; f < 4; ++f) {
            af[f]  = *(const bf16x8*)&As[wm + f * 16 + lcol][lgrp * 8];
            bfr[f] = *(const bf16x8*)&Bs[wn + f * 16 + lcol][lgrp * 8];
        }
#pragma unroll
        for (int fm = 0; fm < 4; ++fm)
#pragma unroll
            for (int fn = 0; fn < 4; ++fn)
                acc[fm][fn] = mfma16(af[fm], bfr[fn], acc[fm][fn]);
        __syncthreads();
    }

#pragma unroll
    for (int fm = 0; fm < 4; ++fm) {
#pragma unroll
        for (int fn = 0; fn < 4; ++fn) {
            int n = n0 + wn + fn * 16 + lcol;
#pragma unroll
            for (int r = 0; r < 4; ++r) {
                int m = m0 + wm + fm * 16 + lgrp * 4 + r;
                float v = acc[fm][fn][r];
                if (EPI == 0) {
                    ob[(size_t)m * N + n] = v;               // f32 output
                } else {
                    int sec = n >> 10, nm = n & 1023;
                    int h = nm >> 6, d = nm & 63;
                    int b = m >> 11, s = m & 2047;
                    size_t bh = (size_t)(b * NH + h);
                    if (sec == 0)      qb[(bh * SL + s) * HD + d]  = (__bf16)(v * QSCALE);
                    else if (sec == 1) kb[(bh * SL + s) * HD + d]  = (__bf16)v;
                    else               vtb[(bh * HD + d) * SL + s] = (__bf16)v;
                }
            }
        }
    }
}

// ---------- flash attention, swapped-operand 32x32 MFMA -----------------------
// grid (SL/128, BSZ*NH), 4 waves x 32 q-rows. Lane owns one q-column.
// S^T = mfma32(K, Q); softmax lane-local; O^T = mfma32(V^T, P^T).
__global__ __launch_bounds__(256) void r5_attn(
    const __bf16* __restrict__ qb, const __bf16* __restrict__ kb,
    const __bf16* __restrict__ vtb, __bf16* __restrict__ ctx)
{
    __shared__ __bf16 Os[4][32][72];     // epilogue transpose bounce (per-wave)
    const int bh   = blockIdx.y;
    const int wave = threadIdx.x >> 6, lane = threadIdx.x & 63;
    const int lq = lane & 31, h = lane >> 5;      // h = lane-half
    const int q0 = blockIdx.x * 128 + wave * 32;
    const __bf16* Q  = qb  + ((size_t)bh * SL + q0) * HD;
    const __bf16* Kp = kb  + (size_t)bh * SL * HD + (size_t)lq * HD + h * 8;
    const __bf16* Vt = vtb + (size_t)bh * HD * SL + h * 8;

    // Q B-frags (col=q=lq, k-elems per hd-subtile t): Q[q0+lq][16t + 8h + j]
    bf16x8 qf[4];
#pragma unroll
    for (int t = 0; t < 4; ++t)
        qf[t] = *(const bf16x8*)&Q[(size_t)lq * HD + t * 16 + h * 8];

    f32x16 accT[2] = {};   // O^T: col=q=lq, row d = 32*dh + (r&3)+8*(r>>2)+4h
    float m_run = -1e30f, l_run = 0.f;

    for (int kb0 = 0; kb0 < SL; kb0 += 32) {
        // S^T[k][q], K as A (row=k), Q as B (col=q); log2 domain (QSCALE has log2e)
        f32x16 s = {};
#pragma unroll
        for (int t = 0; t < 4; ++t) {
            bf16x8 kf = *(const bf16x8*)&Kp[(size_t)kb0 * HD + t * 16];
            s = mfma32(kf, qf[t], s);
        }
        // lane-local softmax for q-col lq (lane halves hold complementary k's)
        float mt = fmaxf(s[0], s[1]);
#pragma unroll
        for (int i = 2; i < 16; ++i) mt = fmaxf(mt, s[i]);
        mt = fmaxf(mt, __shfl_xor(mt, 32));
        float mn = fmaxf(m_run, mt);
        float alpha = exp2f(m_run - mn);
        m_run = mn;
        float p[16];
        float lt = 0.f;
#pragma unroll
        for (int i = 0; i < 16; ++i) { p[i] = exp2f(s[i] - mn); lt += p[i]; }
        lt += __shfl_xor(lt, 32);
        l_run = l_run * alpha + lt;
#pragma unroll
        for (int dh = 0; dh < 2; ++dh)
#pragma unroll
            for (int i = 0; i < 16; ++i) accT[dh][i] *= alpha;
        // P^T B-frags via pack + permlane32_swap (one swap fills two words)
#pragma unroll
        for (int ks = 0; ks < 2; ++ks) {
            const int o = ks * 8;
            uint32_t w0 = pkbf(p[o + 0], p[o + 1]);
            uint32_t w1 = pkbf(p[o + 2], p[o + 3]);
            uint32_t w2 = pkbf(p[o + 4], p[o + 5]);
            uint32_t w3 = pkbf(p[o + 6], p[o + 7]);
            asm volatile("v_permlane32_swap_b32 %0, %1" : "+v"(w0), "+v"(w2));
            asm volatile("v_permlane32_swap_b32 %0, %1" : "+v"(w1), "+v"(w3));
            u32x4 pw = {w0, w1, w2, w3};
            bf16x8 pf = __builtin_bit_cast(bf16x8, pw);
            // O^T += V^T x P^T  (V^T as A: row=d, k-elems = kb0+16ks+8h+j)
#pragma unroll
            for (int dh = 0; dh < 2; ++dh) {
                bf16x8 vf = *(const bf16x8*)&Vt[(size_t)(dh * 32 + lq) * SL + kb0 + ks * 16];
                accT[dh] = mfma32(vf, pf, accT[dh]);
            }
        }
    }

    // epilogue: per-wave LDS transpose -> coalesced bf16 ctx rows
    float inv = 1.f / l_run;
#pragma unroll
    for (int dh = 0; dh < 2; ++dh)
#pragma unroll
        for (int r = 0; r < 16; ++r) {
            int d = dh * 32 + (r & 3) + 8 * (r >> 2) + 4 * h;
            Os[wave][lq][d] = (__bf16)(accT[dh][r] * inv);
        }
    asm volatile("s_waitcnt lgkmcnt(0)" ::: "memory");
    __builtin_amdgcn_sched_barrier(0);
    const int b = bh >> 4, head = bh & 15;
    const int qr = lane >> 1, seg = (lane & 1) * 32;
    __bf16* dst = &ctx[((size_t)b * SL + q0 + qr) * DM + head * HD + seg];
#pragma unroll
    for (int c = 0; c < 4; ++c)
        *(bf16x8*)&dst[c * 8] = *(const bf16x8*)&Os[wave][qr][seg + c * 8];
}

extern "C" void kernel_launch(void* const* d_in, const int* in_sizes, int n_in,
                              void* d_out, int out_size, void* d_ws, size_t ws_size,
                              hipStream_t stream) {
    const float* x    = (const float*)d_in[0];
    const float* wqkv = (const float*)d_in[1];
    const float* wout = (const float*)d_in[2];
    float* out = (float*)d_out;                          // reference returns f32

    __bf16* ws    = (__bf16*)d_ws;
    __bf16* xb    = ws;                                  // 4096*1024
    __bf16* wqkvT = xb    + (size_t)MROWS * DM;          // 3072*1024
    __bf16* woutT = wqkvT + (size_t)3 * DM * DM;         // 1024*1024
    __bf16* qbuf  = woutT + (size_t)DM * DM;             // 32*2048*64
    __bf16* kbuf  = qbuf  + (size_t)MROWS * DM;
    __bf16* vtbuf = kbuf  + (size_t)MROWS * DM;
    __bf16* ctxb  = vtbuf + (size_t)MROWS * DM;

    r5_cast<<<dim3((MROWS * DM) / 1024), dim3(256), 0, stream>>>(x, xb, MROWS * DM);
    r5_transpose_cast<<<dim3(96, 32), dim3(256), 0, stream>>>(wqkv, wqkvT, DM, 3 * DM);
    r5_transpose_cast<<<dim3(32, 32), dim3(256), 0, stream>>>(wout, woutT, DM, DM);

    r5_gemm_bt<1><<<dim3(24, 32), dim3(256), 0, stream>>>(
        xb, wqkvT, (float*)nullptr, MROWS, 3 * DM, DM, qbuf, kbuf, vtbuf);

    r5_attn<<<dim3(16, 32), dim3(256), 0, stream>>>(qbuf, kbuf, vtbuf, ctxb);

    r5_gemm_bt<0><<<dim3(8, 32), dim3(256), 0, stream>>>(
        ctxb, woutT, out, MROWS, DM, DM,
        (__bf16*)nullptr, (__bf16*)nullptr, (__bf16*)nullptr);
}

// Round 6
// 158.439 us; speedup vs baseline: 2.0216x; 1.3557x over previous
//
#include <hip/hip_runtime.h>
#include <cstdint>
#include <cstddef>

typedef float f32x4 __attribute__((ext_vector_type(4)));
typedef float f32x16 __attribute__((ext_vector_type(16)));
typedef __bf16 bf16x8 __attribute__((ext_vector_type(8)));
typedef __bf16 bf16x4 __attribute__((ext_vector_type(4)));
typedef uint32_t u32x4 __attribute__((ext_vector_type(4)));

static constexpr int BSZ = 2, SL = 2048, DM = 1024, NH = 16, HD = 64;
static constexpr int MROWS = BSZ * SL;                 // 4096
static constexpr float LOG2E = 1.4426950408889634f;
static constexpr float QSCALE = 0.03125f * LOG2E;      // D^-0.5 * log2(e)

__device__ __forceinline__ f32x4 mfma16(bf16x8 a, bf16x8 b, f32x4 c) {
    return __builtin_amdgcn_mfma_f32_16x16x32_bf16(a, b, c, 0, 0, 0);
}
__device__ __forceinline__ f32x16 mfma32(bf16x8 a, bf16x8 b, f32x16 c) {
    return __builtin_amdgcn_mfma_f32_32x32x16_bf16(a, b, c, 0, 0, 0);
}
__device__ __forceinline__ uint32_t pkbf(float lo, float hi) {
    uint16_t a = __builtin_bit_cast(uint16_t, (__bf16)lo);
    uint16_t b = __builtin_bit_cast(uint16_t, (__bf16)hi);
    return ((uint32_t)b << 16) | (uint32_t)a;
}

// ---------- cast f32 -> bf16, vectorized x4 ----------
__global__ __launch_bounds__(256) void r6_cast(const float* __restrict__ in,
                                               __bf16* __restrict__ out, int n) {
    int i = (blockIdx.x * 256 + threadIdx.x) * 4;
    if (i >= n) return;
    float4 v = *(const float4*)&in[i];
    bf16x4 o;
    o.x = (__bf16)v.x; o.y = (__bf16)v.y; o.z = (__bf16)v.z; o.w = (__bf16)v.w;
    *(bf16x4*)&out[i] = o;
}

// ---------- transpose [R][C] f32 -> [C][R] bf16 ----------
__global__ __launch_bounds__(256) void r6_transpose_cast(const float* __restrict__ in,
                                                         __bf16* __restrict__ out,
                                                         int R, int C) {
    __shared__ float tile[32][33];
    int c0 = blockIdx.x * 32, r0 = blockIdx.y * 32;
    int tx = threadIdx.x & 31, ty = threadIdx.x >> 5;   // 256 threads: ty 0..7
#pragma unroll
    for (int i = 0; i < 32; i += 8)
        tile[ty + i][tx] = in[(size_t)(r0 + ty + i) * C + c0 + tx];
    __syncthreads();
#pragma unroll
    for (int i = 0; i < 32; i += 8)
        out[(size_t)(c0 + ty + i) * R + r0 + tx] = (__bf16)tile[tx][ty + i];
}

// ---------- GEMM: C[M,N] = A[M,K] * Bt[N,K]^T  (bf16 in, f32 acc) ----------
// EPI==1: scatter into Q (scaled), K, V^T head buffers.  EPI==0: f32 row-major out.
template <int EPI>
__global__ __launch_bounds__(256) void r6_gemm_bt(
    const __bf16* __restrict__ A, const __bf16* __restrict__ Bt,
    float* __restrict__ ob, int M, int N, int K,
    __bf16* __restrict__ qb, __bf16* __restrict__ kb, __bf16* __restrict__ vtb)
{
    constexpr int BM = 128, BN = 128, BK = 32, LDP = 40;  // pad 32->40 elems (80B rows)
    __shared__ __bf16 As[BM][LDP];
    __shared__ __bf16 Bs[BN][LDP];
    const int tid  = threadIdx.x;
    const int m0   = blockIdx.y * BM, n0 = blockIdx.x * BN;
    const int wave = tid >> 6, lane = tid & 63;
    const int lcol = lane & 15, lgrp = lane >> 4;
    const int wm   = (wave >> 1) * 64, wn = (wave & 1) * 64;

    f32x4 acc[4][4] = {};

    for (int k0 = 0; k0 < K; k0 += BK) {
#pragma unroll
        for (int i = 0; i < 2; ++i) {
            int c = tid + 256 * i;
            int row = c >> 2, off = (c & 3) * 8;
            *(int4*)&As[row][off] = *(const int4*)&A[(size_t)(m0 + row) * K + k0 + off];
            *(int4*)&Bs[row][off] = *(const int4*)&Bt[(size_t)(n0 + row) * K + k0 + off];
        }
        __syncthreads();
        bf16x8 af[4], bfr[4];
#pragma unroll
        for (int f = 0; f < 4; ++f) {
            af[f]  = *(const bf16x8*)&As[wm + f * 16 + lcol][lgrp * 8];
            bfr[f] = *(const bf16x8*)&Bs[wn + f * 16 + lcol][lgrp * 8];
        }
#pragma unroll
        for (int fm = 0; fm < 4; ++fm)
#pragma unroll
            for (int fn = 0; fn < 4; ++fn)
                acc[fm][fn] = mfma16(af[fm], bfr[fn], acc[fm][fn]);
        __syncthreads();
    }

#pragma unroll
    for (int fm = 0; fm < 4; ++fm) {
#pragma unroll
        for (int fn = 0; fn < 4; ++fn) {
            int n = n0 + wn + fn * 16 + lcol;
#pragma unroll
            for (int r = 0; r < 4; ++r) {
                int m = m0 + wm + fm * 16 + lgrp * 4 + r;
                float v = acc[fm][fn][r];
                if (EPI == 0) {
                    ob[(size_t)m * N + n] = v;               // f32 output
                } else {
                    int sec = n >> 10, nm = n & 1023;
                    int h = nm >> 6, d = nm & 63;
                    int b = m >> 11, s = m & 2047;
                    size_t bh = (size_t)(b * NH + h);
                    if (sec == 0)      qb[(bh * SL + s) * HD + d]  = (__bf16)(v * QSCALE);
                    else if (sec == 1) kb[(bh * SL + s) * HD + d]  = (__bf16)v;
                    else               vtb[(bh * HD + d) * SL + s] = (__bf16)v;
                }
            }
        }
    }
}

// ---------- flash attention: LDS-staged K/V^T, double-buffered, swizzled ------
// grid (SL/128, BSZ*NH), 4 waves x 32 q-rows, KVBLK=64.
// S^T = mfma32(K, Q); softmax lane-local (defer-max); O^T = mfma32(V^T, P^T).
#define PV_STEP(a0,a1,a2,a3,a4,a5,a6,a7, KS) do {                               \
    uint32_t w0 = pkbf(a0, a1), w1 = pkbf(a2, a3);                              \
    uint32_t w2 = pkbf(a4, a5), w3 = pkbf(a6, a7);                              \
    asm volatile("v_permlane32_swap_b32 %0, %1" : "+v"(w0), "+v"(w2));          \
    asm volatile("v_permlane32_swap_b32 %0, %1" : "+v"(w1), "+v"(w3));          \
    u32x4 pw = {w0, w1, w2, w3};                                                \
    bf16x8 pf = __builtin_bit_cast(bf16x8, pw);                                 \
    const int cv = (((KS) * 2 + h) ^ swz8) * 8;                                 \
    bf16x8 vf0 = *(const bf16x8*)&Vl[lq * 64 + cv];                             \
    bf16x8 vf1 = *(const bf16x8*)&Vl[(lq + 32) * 64 + cv];                      \
    accT0 = mfma32(vf0, pf, accT0);                                             \
    accT1 = mfma32(vf1, pf, accT1);                                             \
} while (0)

__global__ __launch_bounds__(256) void r6_attn(
    const __bf16* __restrict__ qb, const __bf16* __restrict__ kb,
    const __bf16* __restrict__ vtb, __bf16* __restrict__ ctx)
{
    __shared__ __bf16 KV[2][2][4096];    // [buf][K/V][64 rows x 64 cols, swizzled]
    __shared__ __bf16 Os[4][32][72];     // epilogue transpose bounce (per-wave)
    const int bh   = blockIdx.y;
    const int tid  = threadIdx.x;
    const int wave = tid >> 6, lane = tid & 63;
    const int lq = lane & 31, h = lane >> 5;
    const int swz8 = lq & 7;
    const int q0 = blockIdx.x * 128 + wave * 32;

    const __bf16* Q  = qb  + ((size_t)bh * SL + q0) * HD;
    const __bf16* Kg = kb  + (size_t)bh * SL * HD;
    const __bf16* Vg = vtb + (size_t)bh * HD * SL;

    // staging geometry: thread owns 16B chunks (rA,cA) and (rA+32,cA) of each tile
    const int rA = tid >> 3, cA = tid & 7;
    const int sA = cA ^ (rA & 7);              // swizzled slot (same for both chunks)
    const int oA = rA * 64 + sA * 8;           // LDS elem offset; chunk B at +2048

    // Q B-frags (col=q=lq): Q[q0+lq][16t + 8h + j]; Q pre-scaled by D^-0.5*log2e
    bf16x8 qf[4];
#pragma unroll
    for (int t = 0; t < 4; ++t)
        qf[t] = *(const bf16x8*)&Q[(size_t)lq * HD + t * 16 + h * 8];

    f32x16 accT0 = {}, accT1 = {};   // O^T: col=q=lq, row d = 32*dh + (r&3)+8*(r>>2)+4h
    float m_run = -1e30f, l_run = 0.f;

    const __bf16* KgA = Kg + rA * HD + cA * 8;
    const __bf16* VgA = Vg + (size_t)rA * SL + cA * 8;
    int4 kA = *(const int4*)(KgA);
    int4 kB = *(const int4*)(KgA + (size_t)32 * HD);
    int4 vA = *(const int4*)(VgA);
    int4 vB = *(const int4*)(VgA + (size_t)32 * SL);

    for (int t = 0; t < SL / 64; ++t) {
        const int cur = t & 1;
        {   // write staged regs into LDS (swizzled)
            __bf16* dK = &KV[cur][0][oA];
            __bf16* dV = &KV[cur][1][oA];
            *(int4*)dK = kA;  *(int4*)(dK + 2048) = kB;
            *(int4*)dV = vA;  *(int4*)(dV + 2048) = vB;
        }
        if (t + 1 < SL / 64) {   // issue next tile's loads (fly during compute)
            const __bf16* nK = KgA + (size_t)(t + 1) * 64 * HD;
            const __bf16* nV = VgA + (size_t)(t + 1) * 64;
            kA = *(const int4*)(nK);
            kB = *(const int4*)(nK + (size_t)32 * HD);
            vA = *(const int4*)(nV);
            vB = *(const int4*)(nV + (size_t)32 * SL);
        }
        __syncthreads();

        const __bf16* Kl = &KV[cur][0][0];
        const __bf16* Vl = &KV[cur][1][0];

        // QK^T: S^T[k][q] for k rows lq and lq+32
        f32x16 s0 = {}, s1 = {};
        __builtin_amdgcn_s_setprio(1);
#pragma unroll
        for (int t4 = 0; t4 < 4; ++t4) {
            const int cv = ((t4 * 2 + h) ^ swz8) * 8;
            bf16x8 kf0 = *(const bf16x8*)&Kl[lq * 64 + cv];
            bf16x8 kf1 = *(const bf16x8*)&Kl[(lq + 32) * 64 + cv];
            s0 = mfma32(kf0, qf[t4], s0);
            s1 = mfma32(kf1, qf[t4], s1);
        }
        __builtin_amdgcn_s_setprio(0);

        // online softmax (log2 domain), defer-max THR=8
        float t16[16];
#pragma unroll
        for (int i = 0; i < 16; ++i) t16[i] = fmaxf(s0[i], s1[i]);
#pragma unroll
        for (int i = 0; i < 8; ++i) t16[i] = fmaxf(t16[i], t16[i + 8]);
#pragma unroll
        for (int i = 0; i < 4; ++i) t16[i] = fmaxf(t16[i], t16[i + 4]);
        float mt = fmaxf(fmaxf(t16[0], t16[1]), fmaxf(t16[2], t16[3]));
        mt = fmaxf(mt, __shfl_xor(mt, 32));
        if (__any(mt > m_run + 8.f)) {
            float mn = fmaxf(m_run, mt);
            float alpha = exp2f(m_run - mn);
            m_run = mn;
            l_run *= alpha;
            accT0 *= alpha;
            accT1 *= alpha;
        }
        float p0[16], p1[16];
#pragma unroll
        for (int i = 0; i < 16; ++i) {
            p0[i] = exp2f(s0[i] - m_run);
            p1[i] = exp2f(s1[i] - m_run);
        }
        float a16[16];
#pragma unroll
        for (int i = 0; i < 16; ++i) a16[i] = p0[i] + p1[i];
#pragma unroll
        for (int i = 0; i < 8; ++i) a16[i] += a16[i + 8];
#pragma unroll
        for (int i = 0; i < 4; ++i) a16[i] += a16[i + 4];
        float lt = (a16[0] + a16[1]) + (a16[2] + a16[3]);
        lt += __shfl_xor(lt, 32);
        l_run += lt;

        // PV: O^T += V^T x P^T, per 16-k chunk
        __builtin_amdgcn_s_setprio(1);
        PV_STEP(p0[0], p0[1], p0[2], p0[3], p0[4], p0[5], p0[6], p0[7], 0);
        PV_STEP(p0[8], p0[9], p0[10], p0[11], p0[12], p0[13], p0[14], p0[15], 1);
        PV_STEP(p1[0], p1[1], p1[2], p1[3], p1[4], p1[5], p1[6], p1[7], 2);
        PV_STEP(p1[8], p1[9], p1[10], p1[11], p1[12], p1[13], p1[14], p1[15], 3);
        __builtin_amdgcn_s_setprio(0);
    }

    // epilogue: per-wave LDS transpose -> coalesced bf16 ctx rows
    float inv = 1.f / l_run;
#pragma unroll
    for (int r = 0; r < 16; ++r) {
        int d0 = (r & 3) + 8 * (r >> 2) + 4 * h;
        Os[wave][lq][d0]      = (__bf16)(accT0[r] * inv);
        Os[wave][lq][32 + d0] = (__bf16)(accT1[r] * inv);
    }
    asm volatile("s_waitcnt lgkmcnt(0)" ::: "memory");
    __builtin_amdgcn_sched_barrier(0);
    const int b = bh >> 4, head = bh & 15;
    const int qr = lane >> 1, seg = (lane & 1) * 32;
    __bf16* dst = &ctx[((size_t)b * SL + q0 + qr) * DM + head * HD + seg];
#pragma unroll
    for (int c = 0; c < 4; ++c)
        *(bf16x8*)&dst[c * 8] = *(const bf16x8*)&Os[wave][qr][seg + c * 8];
}

extern "C" void kernel_launch(void* const* d_in, const int* in_sizes, int n_in,
                              void* d_out, int out_size, void* d_ws, size_t ws_size,
                              hipStream_t stream) {
    const float* x    = (const float*)d_in[0];
    const float* wqkv = (const float*)d_in[1];
    const float* wout = (const float*)d_in[2];
    float* out = (float*)d_out;                          // reference returns f32

    __bf16* ws    = (__bf16*)d_ws;
    __bf16* xb    = ws;                                  // 4096*1024
    __bf16* wqkvT = xb    + (size_t)MROWS * DM;          // 3072*1024
    __bf16* woutT = wqkvT + (size_t)3 * DM * DM;         // 1024*1024
    __bf16* qbuf  = woutT + (size_t)DM * DM;             // 32*2048*64
    __bf16* kbuf  = qbuf  + (size_t)MROWS * DM;
    __bf16* vtbuf = kbuf  + (size_t)MROWS * DM;
    __bf16* ctxb  = vtbuf + (size_t)MROWS * DM;

    r6_cast<<<dim3((MROWS * DM) / 1024), dim3(256), 0, stream>>>(x, xb, MROWS * DM);
    r6_transpose_cast<<<dim3(96, 32), dim3(256), 0, stream>>>(wqkv, wqkvT, DM, 3 * DM);
    r6_transpose_cast<<<dim3(32, 32), dim3(256), 0, stream>>>(wout, woutT, DM, DM);

    r6_gemm_bt<1><<<dim3(24, 32), dim3(256), 0, stream>>>(
        xb, wqkvT, (float*)nullptr, MROWS, 3 * DM, DM, qbuf, kbuf, vtbuf);

    r6_attn<<<dim3(16, 32), dim3(256), 0, stream>>>(qbuf, kbuf, vtbuf, ctxb);

    r6_gemm_bt<0><<<dim3(8, 32), dim3(256), 0, stream>>>(
        ctxb, woutT, out, MROWS, DM, DM,
        (__bf16*)nullptr, (__bf16*)nullptr, (__bf16*)nullptr);
}